// Round 6
// baseline (3080.994 us; speedup 1.0000x reference)
//
#include <hip/hip_runtime.h>
#include <stdint.h>

// Problem constants (bidirectionalRNN: S=256, B=32, I=H=1024, L=2)
#define SEQ   256
#define BSZ   32
#define HD    1024
#define GD    4096          // 4*H
#define KD    1024
#define MROWS (SEQ*BSZ)     // 8192
#define PBLK  256           // fused persistent grid: 128 blocks/layer, 1 block/CU
#define PTHR  512           // 8 waves: 4 gate-tiles x 2 K-halves

typedef unsigned short u16;
typedef __attribute__((ext_vector_type(8))) __bf16 bf8_t;
typedef __attribute__((ext_vector_type(4))) float  f4_t;
typedef __attribute__((ext_vector_type(4))) unsigned int u4_t;

__device__ __forceinline__ u16 f2bf(float f) {
  unsigned u = __float_as_uint(f);
  u += 0x7fffu + ((u >> 16) & 1u);      // RNE
  return (u16)(u >> 16);
}
__device__ __forceinline__ float sigm(float x) { return 1.0f / (1.0f + __expf(-x)); }
__device__ __forceinline__ float tanh_f(float x) {
  float e = __expf(-2.0f * x);          // inf-safe: x<<0 -> e=inf -> -1
  return 2.0f / (1.0f + e) - 1.0f;
}

// 16B agent-coherent load: bypasses L1+L2 (sc0 sc1), served at MALL.
// NOT compiler-tracked: caller must s_waitcnt vmcnt(0) before using result.
__device__ __forceinline__ u4_t load16_sc(const void* p) {
  u4_t r;
  asm volatile("global_load_dwordx4 %0, %1, off sc0 sc1"
               : "=v"(r) : "v"(p));
  return r;
}

// Stage a 64KB h-slice [32 rows][1024 bf16] into swizzled LDS
// ([32 rows][128 chunks16B], phys chunk = c ^ (row&7)).
// One wave covers rows [rbase, rbase+8), cols c = {lane, lane+64}.
// 16 loads in flight -> single vmcnt(0) -> 16 ds_writes.
__device__ __forceinline__ void stage_h64(const u16* src, uint32_t* lds,
                                          int rbase, int lane) {
  u4_t v[16];
  #pragma unroll
  for (int k = 0; k < 16; k++) {
    int row = rbase + (k >> 1);
    int c   = (k & 1) * 64 + lane;
    v[k] = load16_sc(src + (size_t)row * 1024 + (size_t)c * 8);
  }
  asm volatile("s_waitcnt vmcnt(0)" ::: "memory");
  #pragma unroll
  for (int k = 0; k < 16; k++) {
    int row = rbase + (k >> 1);
    int c   = (k & 1) * 64 + lane;
    int pc  = c ^ (row & 7);
    *(u4_t*)&lds[row * 512 + pc * 4] = v[k];
  }
}

// Same staging but plain cached loads (for replay-deterministic xbf: the
// slice is shared by all 64 blocks of the group -> L2 reuse is wanted).
__device__ __forceinline__ void stage_x64(const u16* src, uint32_t* lds,
                                          int rbase, int lane) {
  #pragma unroll
  for (int k = 0; k < 16; k++) {
    int row = rbase + (k >> 1);
    int c   = (k & 1) * 64 + lane;
    u4_t v  = *(const u4_t*)(src + (size_t)row * 1024 + (size_t)c * 8);
    int pc  = c ^ (row & 7);
    *(u4_t*)&lds[row * 512 + pc * 4] = v;
  }
}

// ---------------- fp32 -> bf16 conversion (x4 vectorized) ----------------
__global__ void cvt_f32_bf16(const float* __restrict__ src, u16* __restrict__ dst, int n4) {
  int i = blockIdx.x * blockDim.x + threadIdx.x;
  if (i >= n4) return;
  float4 v = ((const float4*)src)[i];
  ushort4 o;
  o.x = f2bf(v.x); o.y = f2bf(v.y); o.z = f2bf(v.z); o.w = f2bf(v.w);
  ((ushort4*)dst)[i] = o;
}

// --- weight reorder+convert: gate-interleaved block-owned row layout ------
__global__ void reorder_whh(const float* __restrict__ src, u16* __restrict__ dst, int d) {
  int r = blockIdx.x;                 // 0..8191
  int layer = r >> 12, row = r & 4095;
  int g = row >> 10, j = row & 1023;
  int jblk = j >> 4, jl = j & 15;
  size_t drow = ((size_t)(d * 2 + layer) * 64 + jblk) * 64 + g * 16 + jl;
  float4 v = ((const float4*)(src + (size_t)r * KD))[threadIdx.x];
  ushort4 o;
  o.x = f2bf(v.x); o.y = f2bf(v.y); o.z = f2bf(v.z); o.w = f2bf(v.w);
  ((ushort4*)(dst + drow * KD))[threadIdx.x] = o;
}

// -------- fused persistent 2-layer bidirectional LSTM (ONE dispatch) ------
// 256 blocks x 512 thr, 1 block/CU (144 KB LDS). Block: layer = bid>>7,
// dir d = bid&1, jblk = (bid>>1)&63 -> 16 h-dims, all 4 gates. Wave wv:
// gate mt = wv>>1, K-half kh = wv&1. W_ih + W_hh pinned in VGPRs.
//
// Step schedule (critical-path minimized):
//   head: tid256 polls own root >= 8t (layer1 t==0 also below root >= 8)
//   syncS -> staging (t>0: waves4-7 lH via 16B sc1; t==0: waves0-3 lX)
//   syncA -> MFMA x-path + h-path (t>0) -> lAcc -> syncBC
//   cell (tid<256) -> vmcnt(0) drain -> syncD
//   tid256: sub/root tree RMW (step t published)            } concurrent
//   waves0-3: prefetch lX(t+1) (layer1: poll below root     } after syncD
//             >= 8(t+2) then 16B sc1; layer0: cached xbf)   }
// Layer-0 free-runs ~2x faster than layer-1 -> the tail poll is instant in
// steady state and lX staging is fully off layer-1's head path.
// Coherence: producer sc1 stores drained (vmcnt(0)) before the tree RMW;
// consumer reads are sc1 MALL-direct -> cannot observe staler-than-MALL.
__global__ __launch_bounds__(PTHR, 2) void lstm_persist(
    const u16* __restrict__ whh_r,  // [4 wsel][64 jblk][64 rows][1024] bf16
    const u16* __restrict__ wih_r,  // same layout
    const u16* __restrict__ xbf,    // [8192][1024] bf16 (t-major rows)
    u16*       __restrict__ h0t,    // [2d][8192][1024] bf16 layer-0 trajectory
    u16*       __restrict__ h1t,    // [2d][8192][1024] bf16 layer-1 trajectory
    float*     __restrict__ dout,
    unsigned*  __restrict__ cntb)   // zeroed; region (layer*2+d)*512: root 0, subs 16*(1+s)
{
  const int tid = threadIdx.x;
  const int lane = tid & 63;
  const int wv  = tid >> 6;
  const int mt = wv >> 1, kh = wv & 1;
  const int bid = blockIdx.x;
  const int layer = bid >> 7;
  const int d = bid & 1, jblk = (bid >> 1) & 63;
  const int j0 = jblk * 16;
  const int fr = lane & 15, quad = lane >> 4;
  unsigned* cnt   = cntb + (size_t)(layer * 2 + d) * 512;
  unsigned* cntbl = cntb + (size_t)d * 512;        // layer-0 region (below)

  __builtin_amdgcn_fence(__ATOMIC_ACQUIRE, "agent");   // once: drop stale lines

  __shared__ __align__(16) uint32_t lX[32 * 512];   // 64 KB below-layer input
  __shared__ __align__(16) uint32_t lH[32 * 512];   // 64 KB own h(prev)
  __shared__ __align__(16) float lAcc[4096];        // 16 KB gate partials

  u16*       hme = (layer ? h1t : h0t) + (size_t)d * MROWS * HD;  // own trajectory
  const u16* hbl = h0t + (size_t)d * MROWS * HD;                  // layer-1 lX source

  // ---- one-time weight fragment loads, pinned in VGPRs (128 total) ----
  u4_t wih[16], whh[16];
  {
    const size_t rb = ((size_t)((d * 2 + layer) * 64 + jblk) * 64 + mt * 16 + fr) * KD
                    + kh * 512 + quad * 8;
    #pragma unroll
    for (int ks = 0; ks < 16; ks++) wih[ks] = *(const u4_t*)(wih_r + rb + ks * 32);
    #pragma unroll
    for (int ks = 0; ks < 16; ks++) whh[ks] = *(const u4_t*)(whh_r + rb + ks * 32);
    #pragma unroll
    for (int ks = 0; ks < 16; ks++) {
      asm volatile("" : "+v"(wih[ks]));
      asm volatile("" : "+v"(whh[ks]));   // stop load sinking
    }
  }

  const int b_ = tid >> 3, jp = tid & 7;   // cell phase: tid<256 -> (batch, j-pair)
  float cr0 = 0.0f, cr1 = 0.0f;

  for (int t = 0; t < SEQ; t++) {
    const int tt = d ? (SEQ - 1 - t) : t;

    // ---- head wait: own layer step t-1 done (layer1 t==0: below step 0) ----
    if (tid == 256) {
      const unsigned go = 8u * (unsigned)t;
      long spins = 0;
      for (;;) {
        bool ok = (__hip_atomic_load(&cnt[0], __ATOMIC_RELAXED, __HIP_MEMORY_SCOPE_AGENT) >= go);
        if (ok && layer && t == 0)
          ok = (__hip_atomic_load(&cntbl[0], __ATOMIC_RELAXED, __HIP_MEMORY_SCOPE_AGENT) >= 8u);
        if (ok) break;
        if (++spins > (1L << 22)) break;   // safety escape (deadlock only)
      }
    }
    __syncthreads();                       // S
    asm volatile("" ::: "memory");         // keep staging below the wait

    // ---- head staging ----
    if (t > 0) {
      if (wv >= 4) {                       // lH = own h(prev), MALL 16B loads
        const int ttp = d ? (tt + 1) : (tt - 1);
        stage_h64(hme + (size_t)ttp * BSZ * HD, lH, (wv - 4) * 8, lane);
      }                                    // lX(t) was prefetched at tail of t-1
    } else if (wv < 4) {                   // t == 0: stage lX(0)
      if (layer) stage_h64(hbl + (size_t)tt * BSZ * HD, lX, wv * 8, lane);
      else       stage_x64(xbf + (size_t)(tt * BSZ) * KD, lX, wv * 8, lane);
    }
    __syncthreads();                       // A: lX + lH staged

    // ---- MFMA: x-path always, recurrent path for t>0; same fp32 acc ----
    f4_t acc0 = {}, acc1 = {};
    #pragma unroll
    for (int ks = 0; ks < 16; ks++) {
      int cbase = ((kh * 64 + ks * 4 + quad) ^ (fr & 7)) << 2;   // (fr+16)&7==fr&7
      bf8_t a0 = *(const bf8_t*)&lX[fr * 512 + cbase];
      bf8_t a1 = *(const bf8_t*)&lX[(fr + 16) * 512 + cbase];
      bf8_t wb = __builtin_bit_cast(bf8_t, wih[ks]);
      acc0 = __builtin_amdgcn_mfma_f32_16x16x32_bf16(a0, wb, acc0, 0, 0, 0);
      acc1 = __builtin_amdgcn_mfma_f32_16x16x32_bf16(a1, wb, acc1, 0, 0, 0);
    }
    if (t > 0) {
      #pragma unroll
      for (int ks = 0; ks < 16; ks++) {
        int cbase = ((kh * 64 + ks * 4 + quad) ^ (fr & 7)) << 2;
        bf8_t a0 = *(const bf8_t*)&lH[fr * 512 + cbase];
        bf8_t a1 = *(const bf8_t*)&lH[(fr + 16) * 512 + cbase];
        bf8_t wb = __builtin_bit_cast(bf8_t, whh[ks]);
        acc0 = __builtin_amdgcn_mfma_f32_16x16x32_bf16(a0, wb, acc0, 0, 0, 0);
        acc1 = __builtin_amdgcn_mfma_f32_16x16x32_bf16(a1, wb, acc1, 0, 0, 0);
      }
    }
    // D layout: col=lane&15 (j), row=(lane>>4)*4+r (batch)
    #pragma unroll
    for (int r = 0; r < 4; r++) {
      lAcc[((mt * 2 + kh) * 32 + quad * 4 + r) * 16 + fr]      = acc0[r];
      lAcc[((mt * 2 + kh) * 32 + 16 + quad * 4 + r) * 16 + fr] = acc1[r];
    }
    __syncthreads();                       // BC: lAcc ready

    // ---- cell update: 256 threads x 2 adjacent j each ----
    if (tid < 256) {
      float vg0[4], vg1[4];
      #pragma unroll
      for (int g = 0; g < 4; g++) {
        float2 p0 = *(const float2*)&lAcc[((g * 2 + 0) * 32 + b_) * 16 + 2 * jp];
        float2 p1 = *(const float2*)&lAcc[((g * 2 + 1) * 32 + b_) * 16 + 2 * jp];
        vg0[g] = p0.x + p1.x;
        vg1[g] = p0.y + p1.y;
      }
      float i0 = sigm(vg0[0]), f0 = sigm(vg0[1]), g0 = tanh_f(vg0[2]), o0 = sigm(vg0[3]);
      float i1 = sigm(vg1[0]), f1 = sigm(vg1[1]), g1 = tanh_f(vg1[2]), o1 = sigm(vg1[3]);
      cr0 = f0 * cr0 + i0 * g0;
      cr1 = f1 * cr1 + i1 * g1;
      float hn0 = o0 * tanh_f(cr0), hn1 = o1 * tanh_f(cr1);
      uint32_t hnp = ((uint32_t)f2bf(hn1) << 16) | (uint32_t)f2bf(hn0);

      // own trajectory store (device-coherent write-through, performed at MALL)
      size_t hq = (((size_t)tt * BSZ + b_) * HD + j0 + 2 * jp) >> 1;
      __hip_atomic_store((uint32_t*)hme + hq, hnp, __ATOMIC_RELAXED, __HIP_MEMORY_SCOPE_AGENT);

      if (layer == 1) {
        float2 o2 = make_float2(hn0, hn1);
        *(float2*)&dout[((size_t)tt * BSZ + b_) * (2 * HD) + (size_t)d * HD + j0 + 2 * jp] = o2;
      }
      // h_last/c_last: fwd at final step; bwd at its FIRST step (torch quirk)
      if ((d == 0 && t == SEQ - 1) || (d == 1 && t == 0)) {
        size_t hoff = (size_t)MROWS * 2 * HD + ((size_t)layer * BSZ + b_) * (2 * HD)
                    + (size_t)d * HD + j0 + 2 * jp;
        dout[hoff] = hn0;  dout[hoff + 1] = hn1;
        dout[hoff + (size_t)2 * BSZ * 2 * HD]     = cr0;
        dout[hoff + (size_t)2 * BSZ * 2 * HD + 1] = cr1;
      }
      // drain own sc1 stores to MALL before syncD (flag RMW follows syncD)
      asm volatile("s_waitcnt vmcnt(0)" ::: "memory");
    }

    __syncthreads();                       // D: all cell stores drained

    // ---- publish step t (tid256) ∥ prefetch lX(t+1) (waves 0-3) ----
    if (tid == 256) {
      const unsigned sub = (unsigned)(jblk & 7);
      unsigned old = __hip_atomic_fetch_add(&cnt[16 * (1 + sub)], 1u,
                                            __ATOMIC_RELAXED, __HIP_MEMORY_SCOPE_AGENT);
      if (old + 1u == 8u * (unsigned)(t + 1))
        __hip_atomic_fetch_add(&cnt[0], 1u, __ATOMIC_RELAXED, __HIP_MEMORY_SCOPE_AGENT);
    }
    if (wv < 4 && t + 1 < SEQ) {
      const int ttn = d ? (SEQ - 2 - t) : (t + 1);
      if (layer) {
        // wait for layer-0 step t+1 (root >= 8(t+2)); instant in steady state
        long spins = 0;
        while (__hip_atomic_load(&cntbl[0], __ATOMIC_RELAXED, __HIP_MEMORY_SCOPE_AGENT)
               < 8u * (unsigned)(t + 2)) {
          if (++spins > (1L << 22)) break; // safety escape (deadlock only)
        }
        asm volatile("" ::: "memory");
        stage_h64(hbl + (size_t)ttn * BSZ * HD, lX, wv * 8, lane);
      } else {
        stage_x64(xbf + (size_t)(ttn * BSZ) * KD, lX, wv * 8, lane);
      }
    }
    // lX writes are consumed only after next step's syncA -> safe
  }
}

// -------------------------------------------------------------------------
extern "C" void kernel_launch(void* const* d_in, const int* in_sizes, int n_in,
                              void* d_out, int out_size, void* d_ws, size_t ws_size,
                              hipStream_t stream) {
  const float* x    = (const float*)d_in[0];
  const float* wihf = (const float*)d_in[1];
  const float* whhf = (const float*)d_in[2];
  const float* wihb = (const float*)d_in[3];
  const float* whhb = (const float*)d_in[4];
  float* out = (float*)d_out;

  const size_t NE = (size_t)MROWS * KD;   // 8.4M elems
  u16* ws   = (u16*)d_ws;
  u16* xbf  = ws;                         // [8192][1024] bf16, 16 MB
  u16* whhr = xbf + NE;                   // [4][64][64][1024] bf16, 32 MB
  u16* wihr = whhr + 2 * NE;              // [4][64][64][1024] bf16, 32 MB
  u16* h0   = wihr + 2 * NE;              // [2d][8192][1024] bf16, 32 MB
  u16* h1   = h0 + 2 * NE;                // [2d][8192][1024] bf16, 32 MB
  unsigned* cnt = (unsigned*)(h1 + 2 * NE);  // 4 regions x 512 words

  const int n4 = (int)(NE / 4);
  cvt_f32_bf16<<<n4 / 256, 256, 0, stream>>>(x, xbf, n4);
  reorder_whh<<<2 * GD, 256, 0, stream>>>(whhf, whhr, 0);
  reorder_whh<<<2 * GD, 256, 0, stream>>>(whhb, whhr, 1);
  reorder_whh<<<2 * GD, 256, 0, stream>>>(wihf, wihr, 0);
  reorder_whh<<<2 * GD, 256, 0, stream>>>(wihb, wihr, 1);

  hipMemsetAsync(cnt, 0, 4 * 512 * sizeof(unsigned), stream);

  // single fused dispatch: both layers, both directions, wavefront-pipelined
  lstm_persist<<<PBLK, PTHR, 0, stream>>>(whhr, wihr, xbf, h0, h1, out, cnt);
}